// Round 1
// baseline (250.786 us; speedup 1.0000x reference)
//
#include <hip/hip_runtime.h>
#include <hip/hip_bf16.h>
#include <cmath>

// ---------- problem constants ----------
constexpr int CB = 8, CS = 2048, CDV = 768, CDA = 512, CK = 512;
constexpr int CM = CB * CS;             // 16384 rows (b,s)

// ---------- types ----------
typedef __attribute__((ext_vector_type(8))) short  s8v;   // 8 bf16 (4 VGPRs)
typedef __attribute__((ext_vector_type(4))) short  s4v;   // 4 bf16
typedef __attribute__((ext_vector_type(4))) float  f4v;   // MFMA acc

__device__ __forceinline__ unsigned short f2bf(float x) {
    union { float f; unsigned int u; } c; c.f = x;
    unsigned int u = c.u;
    u += 0x7fffu + ((u >> 16) & 1u);    // RNE (inputs are finite)
    return (unsigned short)(u >> 16);
}

// ---------- prep: bf16 convert + window-3 temporal smooth ----------
template<int D>
__global__ void prep_smooth(const float* __restrict__ f,
                            unsigned short* __restrict__ g,
                            unsigned short* __restrict__ sm)
{
    int idx = blockIdx.x * blockDim.x + threadIdx.x;      // over CB*CS*D/4
    constexpr int total = CB * CS * (D / 4);
    if (idx >= total) return;
    int dchunk = idx % (D / 4);
    int bs     = idx / (D / 4);
    int s      = bs % CS;
    const f4v* fp = (const f4v*)f;
    int base = bs * (D / 4) + dchunk;
    f4v cur = fp[base];
    f4v acc = cur;
    float cnt = 1.f;
    if (s > 0)      { acc += fp[base - D / 4]; cnt += 1.f; }
    if (s < CS - 1) { acc += fp[base + D / 4]; cnt += 1.f; }
    float inv = 1.f / cnt;
    s4v gp, sp;
#pragma unroll
    for (int j = 0; j < 4; ++j) {
        gp[j] = (short)f2bf(cur[j]);
        sp[j] = (short)f2bf(acc[j] * inv);
    }
    ((s4v*)g)[base]  = gp;
    ((s4v*)sm)[base] = sp;
}

// ---------- elementwise fp32 -> bf16 ----------
__global__ void conv_bf16(const float* __restrict__ in, unsigned short* __restrict__ out, int n4)
{
    int i = blockIdx.x * blockDim.x + threadIdx.x;
    if (i >= n4) return;
    f4v v = ((const f4v*)in)[i];
    s4v o;
#pragma unroll
    for (int j = 0; j < 4; ++j) o[j] = (short)f2bf(v[j]);
    ((s4v*)out)[i] = o;
}

// ---------- transpose + convert: in (R x C) fp32 -> out (C x R) bf16 ----------
__global__ void transpose_bf16(const float* __restrict__ in, unsigned short* __restrict__ outp,
                               int R, int C)
{
    int idx = blockIdx.x * blockDim.x + threadIdx.x;
    if (idx >= R * C) return;
    int r = idx % R;                   // consecutive threads -> consecutive r -> coalesced writes
    int c = idx / R;
    outp[(size_t)c * R + r] = f2bf(in[(size_t)r * C + c]);
}

// ---------- shared GEMM tile engine: C(M,N) += A(M,D) @ BT(N,D)^T ----------
// 256 threads = 4 waves; 128x128 tile; each wave owns 64x64 (4x4 frags of 16x16).
// LDS rows padded 64->72 shorts (144B stride -> 4-bank skew, no conflicts).
__device__ __forceinline__ void gemm_phase(
    const unsigned short* __restrict__ A,
    const unsigned short* __restrict__ BT,
    int D, int bm, int bn, int tid,
    unsigned short (*As)[72], unsigned short (*Bs)[72],
    f4v (&acc)[4][4])
{
    const int lane = tid & 63;
    const int w    = tid >> 6;
    const int wr   = (w >> 1) * 64;
    const int wc   = (w & 1) * 64;
    const int lr   = lane & 15;
    const int lk   = (lane >> 4) * 8;

    for (int d0 = 0; d0 < D; d0 += 64) {
        __syncthreads();
#pragma unroll
        for (int it = 0; it < 4; ++it) {
            int idx = it * 256 + tid;
            int r   = idx >> 3;
            int ch  = (idx & 7) * 8;
            *(s8v*)(&As[r][ch]) = *(const s8v*)(A  + (size_t)(bm + r) * D + d0 + ch);
            *(s8v*)(&Bs[r][ch]) = *(const s8v*)(BT + (size_t)(bn + r) * D + d0 + ch);
        }
        __syncthreads();
#pragma unroll
        for (int kk = 0; kk < 2; ++kk) {
            s8v af[4], bfr[4];
#pragma unroll
            for (int f = 0; f < 4; ++f) {
                af[f]  = *(const s8v*)(&As[wr + f * 16 + lr][kk * 32 + lk]);
                bfr[f] = *(const s8v*)(&Bs[wc + f * 16 + lr][kk * 32 + lk]);
            }
#pragma unroll
            for (int i = 0; i < 4; ++i)
#pragma unroll
                for (int j = 0; j < 4; ++j)
                    acc[i][j] = __builtin_amdgcn_mfma_f32_16x16x32_bf16(
                        af[i], bfr[j], acc[i][j], 0, 0, 0);
        }
    }
}

// ---------- small GEMM with bf16 output (proto @ W combine) ----------
__global__ void __launch_bounds__(256)
gemm_combine(const unsigned short* __restrict__ A,
             const unsigned short* __restrict__ BT,
             int D, int N,
             unsigned short* __restrict__ C)
{
    __shared__ __align__(16) unsigned short As[128][72];
    __shared__ __align__(16) unsigned short Bs[128][72];
    f4v acc[4][4] = {};
    int tid = threadIdx.x;
    int bm = blockIdx.x * 128, bn = blockIdx.y * 128;
    gemm_phase(A, BT, D, bm, bn, tid, As, Bs, acc);

    const int lane = tid & 63;
    const int w    = tid >> 6;
    const int wr   = (w >> 1) * 64, wc = (w & 1) * 64;
    const int row0 = (lane >> 4) * 4, col = lane & 15;   // C/D map: col=lane&15, row=(lane>>4)*4+e
#pragma unroll
    for (int i = 0; i < 4; ++i)
#pragma unroll
        for (int j = 0; j < 4; ++j)
#pragma unroll
            for (int e = 0; e < 4; ++e) {
                int m = bm + wr + i * 16 + row0 + e;
                int n = bn + wc + j * 16 + col;
                C[(size_t)m * N + n] = f2bf(acc[i][j][e]);
            }
}

// ---------- fused dual-GEMM + softplus-energy reduce ----------
__global__ void __launch_bounds__(256)
fused_energy(const unsigned short* __restrict__ A1, const unsigned short* __restrict__ B1T, int D1,
             const unsigned short* __restrict__ A2, const unsigned short* __restrict__ B2T, int D2,
             float* __restrict__ out)
{
    __shared__ __align__(16) unsigned short As[128][72];
    __shared__ __align__(16) unsigned short Bs[128][72];
    f4v acc1[4][4] = {};
    f4v acc2[4][4] = {};
    int tid = threadIdx.x;
    int bm = blockIdx.x * 128, bn = blockIdx.y * 128;

    gemm_phase(A1, B1T, D1, bm, bn, tid, As, Bs, acc1);   // intra
    gemm_phase(A2, B2T, D2, bm, bn, tid, As, Bs, acc2);   // cross

    float local = 0.f;
#pragma unroll
    for (int i = 0; i < 4; ++i)
#pragma unroll
        for (int j = 0; j < 4; ++j)
#pragma unroll
            for (int e = 0; e < 4; ++e) {
                float iv = acc1[i][j][e];
                float cv = acc2[i][j][e];
                float sal = 0.3f * cv * cv + 0.7f * iv * iv;
                float t   = sal * iv;
                // stable softplus; fast log/exp fine vs 2% tolerance
                local += fmaxf(t, 0.f) + __logf(1.f + __expf(-fabsf(t)));
            }
    // wave reduce (64 lanes)
#pragma unroll
    for (int o = 32; o > 0; o >>= 1) local += __shfl_down(local, o);
    __shared__ float wred[4];
    int lane = tid & 63, w = tid >> 6;
    if (lane == 0) wred[w] = local;
    __syncthreads();
    if (tid == 0) atomicAdd(out, -(wred[0] + wred[1] + wred[2] + wred[3]));
}

// ---------- launch ----------
extern "C" void kernel_launch(void* const* d_in, const int* in_sizes, int n_in,
                              void* d_out, int out_size, void* d_ws, size_t ws_size,
                              hipStream_t stream)
{
    const float* fv = (const float*)d_in[0];   // (8,2048,768)
    const float* fa = (const float*)d_in[1];   // (8,2048,512)
    const float* pv = (const float*)d_in[2];   // (512,768)
    const float* pa = (const float*)d_in[3];   // (512,512)
    const float* wv = (const float*)d_in[4];   // (768,512) proj_audio_to_vision
    const float* wa = (const float*)d_in[5];   // (512,768) proj_vision_to_audio
    float* out = (float*)d_out;

    size_t off = 0;
    auto carve = [&](size_t elems) {
        unsigned short* p = (unsigned short*)((char*)d_ws + off);
        off += ((elems * 2 + 255) & ~(size_t)255);
        return p;
    };
    unsigned short* Gv  = carve((size_t)CM * CDV);   // bf16 feat_vision
    unsigned short* Sv  = carve((size_t)CM * CDV);   // bf16 smooth(feat_vision)
    unsigned short* Ga  = carve((size_t)CM * CDA);
    unsigned short* Sa  = carve((size_t)CM * CDA);
    unsigned short* Pv  = carve((size_t)CK * CDV);   // proto_vision bf16
    unsigned short* Pa  = carve((size_t)CK * CDA);
    unsigned short* WvT = carve((size_t)CDA * CDV);  // (512,768) = proj_a2v^T
    unsigned short* WaT = carve((size_t)CDV * CDA);  // (768,512) = proj_v2a^T
    unsigned short* Cv  = carve((size_t)CK * CDA);   // P_comb vision (512,512)
    unsigned short* Ca  = carve((size_t)CK * CDV);   // P_comb audio  (512,768)

    hipMemsetAsync(d_out, 0, sizeof(float), stream);

    prep_smooth<CDV><<<(CM * CDV / 4 + 255) / 256, 256, 0, stream>>>(fv, Gv, Sv);
    prep_smooth<CDA><<<(CM * CDA / 4 + 255) / 256, 256, 0, stream>>>(fa, Ga, Sa);
    conv_bf16<<<(CK * CDV / 4 + 255) / 256, 256, 0, stream>>>(pv, Pv, CK * CDV / 4);
    conv_bf16<<<(CK * CDA / 4 + 255) / 256, 256, 0, stream>>>(pa, Pa, CK * CDA / 4);
    transpose_bf16<<<(CDV * CDA + 255) / 256, 256, 0, stream>>>(wv, WvT, CDV, CDA); // -> (512,768)
    transpose_bf16<<<(CDV * CDA + 255) / 256, 256, 0, stream>>>(wa, WaT, CDA, CDV); // -> (768,512)

    // P_comb_v[k,c] = sum_d proto_v[k,d] * Wv[d,c]  : A=Pv(512x768), BT=WvT(512x768), N=512
    gemm_combine<<<dim3(4, 4), 256, 0, stream>>>(Pv, WvT, CDV, CDA, Cv);
    // P_comb_a[k,c] = sum_d proto_a[k,d] * Wa[d,c]  : A=Pa(512x512), BT=WaT(768x512), N=768
    gemm_combine<<<dim3(4, 6), 256, 0, stream>>>(Pa, WaT, CDA, CDV, Ca);

    // e_v: intra = Gv @ Pv^T (D=768); cross = Sa @ Cv^T (D=512)
    fused_energy<<<dim3(CM / 128, CK / 128), 256, 0, stream>>>(Gv, Pv, CDV, Sa, Cv, CDA, out);
    // e_a: intra = Ga @ Pa^T (D=512); cross = Sv @ Ca^T (D=768)
    fused_energy<<<dim3(CM / 128, CK / 128), 256, 0, stream>>>(Ga, Pa, CDA, Sv, Ca, CDV, out);
}

// Round 2
// 220.905 us; speedup vs baseline: 1.1353x; 1.1353x over previous
//
#include <hip/hip_runtime.h>
#include <hip/hip_bf16.h>
#include <cmath>

// ---------- problem constants ----------
constexpr int CB = 8, CS = 2048, CDV = 768, CDA = 512, CK = 512;
constexpr int CM = CB * CS;             // 16384 rows (b,s)

// ---------- types ----------
typedef __attribute__((ext_vector_type(8))) short  s8v;   // 8 bf16 (4 VGPRs)
typedef __attribute__((ext_vector_type(4))) short  s4v;   // 4 bf16
typedef __attribute__((ext_vector_type(4))) float  f4v;   // MFMA acc

__device__ __forceinline__ unsigned short f2bf(float x) {
    union { float f; unsigned int u; } c; c.f = x;
    unsigned int u = c.u;
    u += 0x7fffu + ((u >> 16) & 1u);    // RNE (inputs finite)
    return (unsigned short)(u >> 16);
}

// ---------- prep: bf16 convert + window-3 temporal smooth (both modalities) ----------
template<int D>
__device__ __forceinline__ void smooth_one(const float* __restrict__ f,
                                           unsigned short* __restrict__ g,
                                           unsigned short* __restrict__ sm,
                                           int idx)
{
    int dchunk = idx % (D / 4);
    int bs     = idx / (D / 4);
    int s      = bs % CS;
    const f4v* fp = (const f4v*)f;
    int base = bs * (D / 4) + dchunk;
    f4v cur = fp[base];
    f4v acc = cur;
    float cnt = 1.f;
    if (s > 0)      { acc += fp[base - D / 4]; cnt += 1.f; }
    if (s < CS - 1) { acc += fp[base + D / 4]; cnt += 1.f; }
    float inv = 1.f / cnt;
    s4v gp, sp;
#pragma unroll
    for (int j = 0; j < 4; ++j) {
        gp[j] = (short)f2bf(cur[j]);
        sp[j] = (short)f2bf(acc[j] * inv);
    }
    ((s4v*)g)[base]  = gp;
    ((s4v*)sm)[base] = sp;
}

__global__ void prep_smooth_all(const float* __restrict__ fv, const float* __restrict__ fa,
                                unsigned short* __restrict__ Gv, unsigned short* __restrict__ Sv,
                                unsigned short* __restrict__ Ga, unsigned short* __restrict__ Sa)
{
    int idx = blockIdx.x * 256 + threadIdx.x;
    constexpr int NV = CM * (CDV / 4);
    constexpr int NA = CM * (CDA / 4);
    if (idx < NV)            smooth_one<CDV>(fv, Gv, Sv, idx);
    else if (idx < NV + NA)  smooth_one<CDA>(fa, Ga, Sa, idx - NV);
}

// ---------- small prep: proto convert + proj transpose (one launch) ----------
__device__ __forceinline__ void conv4(const float* __restrict__ in,
                                      unsigned short* __restrict__ out, int i)
{
    f4v v = ((const f4v*)in)[i];
    s4v o;
#pragma unroll
    for (int j = 0; j < 4; ++j) o[j] = (short)f2bf(v[j]);
    ((s4v*)out)[i] = o;
}

__global__ void prep_small(const float* __restrict__ pv, const float* __restrict__ pa,
                           const float* __restrict__ wv, const float* __restrict__ wa,
                           unsigned short* __restrict__ Pv, unsigned short* __restrict__ Pa,
                           unsigned short* __restrict__ WvT, unsigned short* __restrict__ WaT)
{
    int idx = blockIdx.x * 256 + threadIdx.x;
    constexpr int N1 = CK * CDV / 4;
    constexpr int N2 = CK * CDA / 4;
    constexpr int N3 = CDV * CDA;
    constexpr int N4 = CDV * CDA;
    if (idx < N1) { conv4(pv, Pv, idx); return; }
    idx -= N1;
    if (idx < N2) { conv4(pa, Pa, idx); return; }
    idx -= N2;
    if (idx < N3) {   // wv (768x512) -> WvT (512x768): WvT[c*768+r] = wv[r*512+c]
        int r = idx % CDV, c = idx / CDV;
        WvT[(size_t)c * CDV + r] = f2bf(wv[(size_t)r * CDA + c]);
        return;
    }
    idx -= N3;
    if (idx < N4) {   // wa (512x768) -> WaT (768x512): WaT[c*512+r] = wa[r*768+c]
        int r = idx % CDA, c = idx / CDA;
        WaT[(size_t)c * CDA + r] = f2bf(wa[(size_t)r * CDV + c]);
    }
}

// ---------- GEMM tile engine: acc += A(M,D) @ BT(N,D)^T on a 128x128 tile ----------
// 256 threads = 4 waves, each wave owns 64x64 (4x4 frags of 16x16x32 bf16).
// LDS is LINEAR [128 rows][64 shorts] so global_load_lds (16B/lane) applies.
// Bank-conflict fix (both-sides XOR, rule #21): global source chunk is
// pre-swizzled ch^=(row&7); fragment reads apply the same XOR.
__device__ __forceinline__ void gemm_phase(
    const unsigned short* __restrict__ A,
    const unsigned short* __restrict__ BT,
    int D, int bm, int bn, int tid,
    unsigned short* As, unsigned short* Bs,   // 128*64 shorts each
    f4v (&acc)[4][4])
{
    const int lane = tid & 63;
    const int w    = tid >> 6;
    const int wr   = (w >> 1) * 64;
    const int wc   = (w & 1) * 64;
    const int lr   = lane & 15;
    const int hi   = lane >> 4;

    for (int d0 = 0; d0 < D; d0 += 64) {
        __syncthreads();               // previous compute done before overwrite
#pragma unroll
        for (int it = 0; it < 4; ++it) {
            int idx  = it * 256 + tid;
            int row  = idx >> 3;
            int sch  = (idx & 7) ^ (row & 7);          // pre-swizzled source chunk
            int wbase = (idx & ~63) * 8;               // wave-uniform LDS base (shorts)
            const unsigned short* gA = A  + (size_t)(bm + row) * D + d0 + sch * 8;
            const unsigned short* gB = BT + (size_t)(bn + row) * D + d0 + sch * 8;
            __builtin_amdgcn_global_load_lds(
                (const __attribute__((address_space(1))) unsigned int*)gA,
                (__attribute__((address_space(3))) unsigned int*)(As + wbase), 16, 0, 0);
            __builtin_amdgcn_global_load_lds(
                (const __attribute__((address_space(1))) unsigned int*)gB,
                (__attribute__((address_space(3))) unsigned int*)(Bs + wbase), 16, 0, 0);
        }
        asm volatile("s_waitcnt vmcnt(0)" ::: "memory");
        __syncthreads();
#pragma unroll
        for (int kk = 0; kk < 2; ++kk) {
            s8v af[4], bfr[4];
#pragma unroll
            for (int f = 0; f < 4; ++f) {
                int ar = wr + f * 16 + lr;
                int ac = ((kk * 4 + hi) ^ (ar & 7)) * 8;   // swizzled read
                af[f]  = *(const s8v*)(As + ar * 64 + ac);
                int br = wc + f * 16 + lr;
                int bc = ((kk * 4 + hi) ^ (br & 7)) * 8;
                bfr[f] = *(const s8v*)(Bs + br * 64 + bc);
            }
#pragma unroll
            for (int i = 0; i < 4; ++i)
#pragma unroll
                for (int j = 0; j < 4; ++j)
                    acc[i][j] = __builtin_amdgcn_mfma_f32_16x16x32_bf16(
                        af[i], bfr[j], acc[i][j], 0, 0, 0);
        }
    }
}

// ---------- combine GEMMs (both modalities, one launch), bf16 out ----------
__global__ void __launch_bounds__(256)
gemm_combine2(const unsigned short* __restrict__ Pv, const unsigned short* __restrict__ WvT,
              unsigned short* __restrict__ Cv,
              const unsigned short* __restrict__ Pa, const unsigned short* __restrict__ WaT,
              unsigned short* __restrict__ Ca)
{
    __shared__ __align__(16) unsigned short As[128 * 64];
    __shared__ __align__(16) unsigned short Bs[128 * 64];
    int id = blockIdx.x;
    const unsigned short *A, *BT; unsigned short* C; int D, N, bm, bn;
    if (id < 16) { A = Pv; BT = WvT; C = Cv; D = CDV; N = CDA; bm = (id & 3) * 128; bn = (id >> 2) * 128; }
    else { id -= 16; A = Pa; BT = WaT; C = Ca; D = CDA; N = CDV; bm = (id & 3) * 128; bn = (id >> 2) * 128; }

    f4v acc[4][4] = {};
    int tid = threadIdx.x;
    gemm_phase(A, BT, D, bm, bn, tid, As, Bs, acc);

    const int lane = tid & 63;
    const int w    = tid >> 6;
    const int wr   = (w >> 1) * 64, wc = (w & 1) * 64;
    const int row0 = (lane >> 4) * 4, col = lane & 15;   // C/D map: col=lane&15, row=(lane>>4)*4+e
#pragma unroll
    for (int i = 0; i < 4; ++i)
#pragma unroll
        for (int j = 0; j < 4; ++j)
#pragma unroll
            for (int e = 0; e < 4; ++e) {
                int m = bm + wr + i * 16 + row0 + e;
                int n = bn + wc + j * 16 + col;
                C[(size_t)m * N + n] = f2bf(acc[i][j][e]);
            }
}

// ---------- fused dual-GEMM + softplus-energy reduce (both modalities via z) ----------
__global__ void __launch_bounds__(256)
fused_energy(const unsigned short* __restrict__ Gv, const unsigned short* __restrict__ Pv,
             const unsigned short* __restrict__ Ga, const unsigned short* __restrict__ Pa,
             const unsigned short* __restrict__ Sa, const unsigned short* __restrict__ Cv,
             const unsigned short* __restrict__ Sv, const unsigned short* __restrict__ Ca,
             float* __restrict__ out)
{
    __shared__ __align__(16) unsigned short As[128 * 64];
    __shared__ __align__(16) unsigned short Bs[128 * 64];
    const unsigned short *A1, *B1, *A2, *B2; int D1, D2;
    if (blockIdx.z == 0) { A1 = Gv; B1 = Pv; D1 = CDV; A2 = Sa; B2 = Cv; D2 = CDA; }
    else                 { A1 = Ga; B1 = Pa; D1 = CDA; A2 = Sv; B2 = Ca; D2 = CDV; }

    f4v acc1[4][4] = {};
    f4v acc2[4][4] = {};
    int tid = threadIdx.x;
    int bm = blockIdx.x * 128, bn = blockIdx.y * 128;

    gemm_phase(A1, B1, D1, bm, bn, tid, As, Bs, acc1);   // intra
    gemm_phase(A2, B2, D2, bm, bn, tid, As, Bs, acc2);   // cross

    float local = 0.f;
#pragma unroll
    for (int i = 0; i < 4; ++i)
#pragma unroll
        for (int j = 0; j < 4; ++j)
#pragma unroll
            for (int e = 0; e < 4; ++e) {
                float iv = acc1[i][j][e];
                float cv = acc2[i][j][e];
                float sal = 0.3f * cv * cv + 0.7f * iv * iv;
                float t   = sal * iv;
                local += fmaxf(t, 0.f) + __logf(1.f + __expf(-fabsf(t)));
            }
#pragma unroll
    for (int o = 32; o > 0; o >>= 1) local += __shfl_down(local, o);
    __shared__ float wred[4];
    int lane = tid & 63, w = tid >> 6;
    if (lane == 0) wred[w] = local;
    __syncthreads();
    if (tid == 0) atomicAdd(out, -(wred[0] + wred[1] + wred[2] + wred[3]));
}

// ---------- launch ----------
extern "C" void kernel_launch(void* const* d_in, const int* in_sizes, int n_in,
                              void* d_out, int out_size, void* d_ws, size_t ws_size,
                              hipStream_t stream)
{
    const float* fv = (const float*)d_in[0];   // (8,2048,768)
    const float* fa = (const float*)d_in[1];   // (8,2048,512)
    const float* pv = (const float*)d_in[2];   // (512,768)
    const float* pa = (const float*)d_in[3];   // (512,512)
    const float* wv = (const float*)d_in[4];   // (768,512) proj_audio_to_vision
    const float* wa = (const float*)d_in[5];   // (512,768) proj_vision_to_audio
    float* out = (float*)d_out;

    size_t off = 0;
    auto carve = [&](size_t elems) {
        unsigned short* p = (unsigned short*)((char*)d_ws + off);
        off += ((elems * 2 + 255) & ~(size_t)255);
        return p;
    };
    unsigned short* Gv  = carve((size_t)CM * CDV);
    unsigned short* Sv  = carve((size_t)CM * CDV);
    unsigned short* Ga  = carve((size_t)CM * CDA);
    unsigned short* Sa  = carve((size_t)CM * CDA);
    unsigned short* Pv  = carve((size_t)CK * CDV);
    unsigned short* Pa  = carve((size_t)CK * CDA);
    unsigned short* WvT = carve((size_t)CDA * CDV);
    unsigned short* WaT = carve((size_t)CDV * CDA);
    unsigned short* Cv  = carve((size_t)CK * CDA);
    unsigned short* Ca  = carve((size_t)CK * CDV);

    hipMemsetAsync(d_out, 0, sizeof(float), stream);

    constexpr int NS = CM * (CDV / 4) + CM * (CDA / 4);
    prep_smooth_all<<<(NS + 255) / 256, 256, 0, stream>>>(fv, fa, Gv, Sv, Ga, Sa);

    constexpr int NP = CK * CDV / 4 + CK * CDA / 4 + 2 * CDV * CDA;
    prep_small<<<(NP + 255) / 256, 256, 0, stream>>>(pv, pa, wv, wa, Pv, Pa, WvT, WaT);

    gemm_combine2<<<16 + 24, 256, 0, stream>>>(Pv, WvT, Cv, Pa, WaT, Ca);

    fused_energy<<<dim3(CM / 128, CK / 128, 2), 256, 0, stream>>>(
        Gv, Pv, Ga, Pa, Sa, Cv, Sv, Ca, out);
}